// Round 4
// baseline (124.795 us; speedup 1.0000x reference)
//
#include <hip/hip_runtime.h>

#define NROWS 8192
#define KDIM  256
#define NT    64                  // NROWS / 128
#define NBLK  (NT * (NT + 1) / 2) // 2080 upper-triangular 128x128 tiles
#define GRID  256                 // persistent blocks; contiguous 8-9 tile chunks

typedef __attribute__((ext_vector_type(4)))  float f32x4;
typedef __attribute__((ext_vector_type(16))) float f32x16;
typedef __attribute__((ext_vector_type(4)))  int   i32x4;
typedef __attribute__((ext_vector_type(8)))  int   i32x8;

// async global->LDS, 16B per lane; LDS dest is wave-uniform base + lane*16
#define GLD(gp, lp)                                                            \
  __builtin_amdgcn_global_load_lds(                                            \
      (const __attribute__((address_space(1))) void*)(gp),                     \
      (__attribute__((address_space(3))) void*)(lp), 16, 0, 0)

// ---------------------------------------------------------------------------
// Kernel 1: fp32 -> fp8 e4m3 (OCP) convert + per-row meta {sumsq/256, label}.
// 256 blocks x 256 threads, one wave per row (grid-stride, 8 rows/wave).
// float4 loads (16B/lane), 4 fp8 bytes packed per lane, coalesced uint store.
// Also zeroes out[0] (pair_kernel atomics accumulate the final scalar there).
// ---------------------------------------------------------------------------
__global__ __launch_bounds__(256) void prep_kernel(
    const float* __restrict__ samples, const int* __restrict__ labels,
    unsigned char* __restrict__ sf8, float2* __restrict__ meta,
    float* __restrict__ out) {
  int tid = blockIdx.x * 256 + threadIdx.x;
  int gw = tid >> 6;        // global wave id, 0..1023
  int lane = tid & 63;
#pragma unroll
  for (int it = 0; it < NROWS / 1024; ++it) {
    int row = gw + it * 1024;
    f32x4 v = ((const f32x4*)samples)[(size_t)row * 64 + lane];
    int pk = __builtin_amdgcn_cvt_pk_fp8_f32(v.x, v.y, 0, false);
    pk = __builtin_amdgcn_cvt_pk_fp8_f32(v.z, v.w, pk, true);
    ((unsigned int*)sf8)[(size_t)row * 64 + lane] = (unsigned int)pk;
    float p = v.x * v.x + v.y * v.y + v.z * v.z + v.w * v.w;
#pragma unroll
    for (int off = 32; off; off >>= 1) p += __shfl_down(p, off);
    if (lane == 0)
      meta[row] = make_float2(p * (1.0f / 256.0f), (float)labels[row]);
  }
  if (tid == 0) out[0] = 0.0f;
}

// decode triangular index b -> (bi, bj), bi <= bj  (verified over 0..NBLK-1)
__device__ inline void decode_tile(int b, int& bi, int& bj) {
  float disc = (2.0f * NT + 1.0f) * (2.0f * NT + 1.0f) - 8.0f * (float)b;
  bi = (int)(((2.0f * NT + 1.0f) - sqrtf(disc)) * 0.5f);
  if (bi < 0) bi = 0;
  if (bi > NT - 1) bi = NT - 1;
  while (bi > 0 && (bi * NT - bi * (bi - 1) / 2) > b) --bi;
  while (((bi + 1) * NT - (bi + 1) * bi / 2) <= b) ++bi;
  bj = bi + (b - (bi * NT - bi * (bi - 1) / 2));
}

// ---------------------------------------------------------------------------
// Kernel 2: persistent blocks over CONTIGUOUS row-major chunks of the upper
// triangle (block c -> tiles [c*65/8, (c+1)*65/8)), so bi is constant for
// ~8 tiles: the A panel is RE-STAGED ONLY ON ROW CHANGE (independent A/B
// double buffers, 128 KB LDS total). Avg staged bytes/tile 64->36 KB, which
// now fits under the MFMA+LDS compute window -> no exposed vmcnt stall.
// XCD-chunked swizzle ((b&7)*32 + b>>3) gives each XCD a contiguous triangle
// region whose panels stay local-L2-resident.
// 8 waves, each a 32x64 quadrant (2x mfma_scale 32x32x64 fp8, scale=1.0).
// Deferred epilogue (T15): two acc banks ping-pong; tile t's epilogue VALU
// runs inside tile t+1's MFMA phase. One barrier per tile; one scaled atomic
// into out[0] per block.
// ---------------------------------------------------------------------------
__global__ __launch_bounds__(512, 1) void pair_kernel(
    const unsigned char* __restrict__ sf8, const float2* __restrict__ meta,
    float* __restrict__ out) {

  __shared__ __align__(16) unsigned char As[2][128 * 256];
  __shared__ __align__(16) unsigned char Bs[2][128 * 256];
  __shared__ float red[8];

  int t = threadIdx.x;
  int lane = t & 63;
  int w = t >> 6;               // 0..7
  int wm = w >> 1, wn = w & 1;  // wave quadrant: rows wm*32+, cols wn*64+
  int lr = lane >> 4, pc = lane & 15;  // staging: row-in-region, phys chunk
  int l31 = lane & 31;                 // fragment row/col within 32
  int hk  = lane >> 5;                 // k-half selector (0/1)

  float stt = 0.f;

  // stage one 128-row panel into buffer `buf`: 32 regions x 1KB,
  // XOR-16B swizzle applied on the GLOBAL side (LDS base stays wave-uniform)
  auto stage_A = [&](int bi_, int buf) {
    int rA = bi_ * 128;
#pragma unroll
    for (int p = 0; p < 4; ++p) {
      int region = p * 8 + w;
      int rr = region * 4 + lr;
      int c = pc ^ (rr & 15);
      GLD(sf8 + (size_t)(rA + rr) * KDIM + c * 16, &As[buf][region * 1024]);
    }
  };
  auto stage_B = [&](int bj_, int buf) {
    int rB = bj_ * 128;
#pragma unroll
    for (int p = 0; p < 4; ++p) {
      int region = p * 8 + w;
      int rr = region * 4 + lr;
      int c = pc ^ (rr & 15);
      GLD(sf8 + (size_t)(rB + rr) * KDIM + c * 16, &Bs[buf][region * 1024]);
    }
  };

  // XCD-chunked bijective swizzle: XCD x (blocks b%8==x) owns chunks x*32..+31
  int cid = (blockIdx.x & 7) * 32 + (blockIdx.x >> 3);
  int t0 = (cid * 65) >> 3, t1 = ((cid + 1) * 65) >> 3;  // 2080/256 = 65/8
  int ntile = t1 - t0;  // 8 or 9

  int bi, bj;
  decode_tile(t0, bi, bj);
  stage_A(bi, 0);
  stage_B(bj, 0);
  int acur = 0, bcur = 0;

  // deferred-epilogue state (scalars reloaded per iter; meta is L2-resident)
  int pbi = 0, pbj = 0;
  float sqa[16], laa[16], sqb[2], labv[2], pwt = 1.f;
  f32x16 accA[2], accB[2];

  // per-row scalars for the deferred tile; issued BEFORE prefetch GLDs so
  // their (in-order) vmcnt waits don't force prefetch completion.
  // C/D layout (32x32): col = lane&31, row = (reg&3)+8*(reg>>2)+4*(lane>>5)
  auto load_scalars = [&](int pbi_, int pbj_) {
#pragma unroll
    for (int g = 0; g < 4; ++g) {
      int gr = pbi_ * 128 + wm * 32 + g * 8 + 4 * hk;  // rows gr..gr+3
      f32x4 m0 = *(const f32x4*)(meta + gr);
      f32x4 m1 = *(const f32x4*)(meta + gr + 2);
      sqa[g * 4 + 0] = m0.x; laa[g * 4 + 0] = m0.y;
      sqa[g * 4 + 1] = m0.z; laa[g * 4 + 1] = m0.w;
      sqa[g * 4 + 2] = m1.x; laa[g * 4 + 2] = m1.y;
      sqa[g * 4 + 3] = m1.z; laa[g * 4 + 3] = m1.w;
    }
#pragma unroll
    for (int j = 0; j < 2; ++j) {
      float2 mb = meta[pbj_ * 128 + wn * 64 + j * 32 + l31];
      sqb[j] = mb.x; labv[j] = mb.y;
    }
    pwt = (pbi_ == pbj_) ? 1.0f : 2.0f;
  };

  // MFMA phase on As[acur]/Bs[bcur]: 8x mfma_scale 32x32x64 fp8 (e8m0 127=1.0)
  auto domfma = [&](f32x16 (&acc)[2]) {
#pragma unroll
    for (int j = 0; j < 2; ++j)
#pragma unroll
      for (int e = 0; e < 16; ++e) acc[j][e] = 0.f;
    const unsigned char* Ab = &As[acur][0];
    const unsigned char* Bb = &Bs[bcur][0];
#pragma unroll
    for (int kt = 0; kt < 4; ++kt) {
      int c0 = kt * 4 + hk * 2;  // logical 16B-chunk pair for this lane
      int m = wm * 32 + l31;
      const unsigned char* ab = Ab + m * 256;
      int sm = m & 15;
      i32x4 alo = *(const i32x4*)(ab + ((c0 ^ sm) << 4));
      i32x4 ahi = *(const i32x4*)(ab + (((c0 + 1) ^ sm) << 4));
      i32x8 av = {alo.x, alo.y, alo.z, alo.w, ahi.x, ahi.y, ahi.z, ahi.w};
#pragma unroll
      for (int j = 0; j < 2; ++j) {
        int n = wn * 64 + j * 32 + l31;
        const unsigned char* bb = Bb + n * 256;
        int sn = n & 15;
        i32x4 blo = *(const i32x4*)(bb + ((c0 ^ sn) << 4));
        i32x4 bhi = *(const i32x4*)(bb + (((c0 + 1) ^ sn) << 4));
        i32x8 bv = {blo.x, blo.y, blo.z, blo.w, bhi.x, bhi.y, bhi.z, bhi.w};
        acc[j] = __builtin_amdgcn_mfma_scale_f32_32x32x64_f8f6f4(
            av, bv, acc[j], 0, 0, 0, 127, 0, 127);
      }
    }
  };

  // epilogue for the deferred tile: gram -> S -> hinge/same, one accumulator
  auto epi = [&](const f32x16 (&acc)[2]) {
    float s = 0.f;
#pragma unroll
    for (int j = 0; j < 2; ++j) {
#pragma unroll
      for (int g2 = 0; g2 < 16; ++g2) {
        float S = sqa[g2] + sqb[j] - acc[j][g2] * (1.0f / 128.0f);
        float h = fmaxf(0.f, 1.f - S);
        s += (laa[g2] == labv[j]) ? S : h;
      }
    }
    stt += pwt * s;
  };

  for (int k = 0; k < ntile; ++k) {
    bool have_next = (k + 1 < ntile);
    int nbi = bi, nbj = bj + 1;
    if (nbj == NT) { nbi = bi + 1; nbj = nbi; }  // row-major triangle walk

    __syncthreads();  // current buffers staged (vmcnt drain at barrier)

    if (k > 0) load_scalars(pbi, pbj);  // L2-hit loads, consumed in epi

    if (have_next) {
      stage_B(nbj, bcur ^ 1);                   // async prefetch
      if (nbi != bi) stage_A(nbi, acur ^ 1);    // A only on row change
    }

    // MFMA(cur tile) interleaved (separate pipes) with epilogue(prev tile)
    if (k & 1) {
      domfma(accB);
      if (k > 0) epi(accA);
    } else {
      domfma(accA);
      if (k > 0) epi(accB);
    }

    pbi = bi; pbj = bj;
    if (have_next) {
      if (nbi != bi) acur ^= 1;
      bcur ^= 1;
      bi = nbi; bj = nbj;
    }
  }

  // drain: epilogue for the last computed tile (bank = parity of ntile-1)
  load_scalars(pbi, pbj);
  if ((ntile - 1) & 1) epi(accB);
  else                 epi(accA);

  // ---- once per block: reduce 8 waves, 1 scaled atomic into out[0] ----
#pragma unroll
  for (int off = 32; off; off >>= 1) stt += __shfl_down(stt, off);
  if (lane == 0) red[w] = stt;
  __syncthreads();
  if (t == 0) {
    float a = 0.f;
#pragma unroll
    for (int q = 0; q < 8; q++) a += red[q];
    atomicAdd(&out[0], a * (10.0f / ((float)NROWS * (float)NROWS)));
  }
}

extern "C" void kernel_launch(void* const* d_in, const int* in_sizes, int n_in,
                              void* d_out, int out_size, void* d_ws,
                              size_t ws_size, hipStream_t stream) {
  // inputs: 0=merged (unused), 1=input1 (unused), 2=samples, 3=labels
  const float* samples = (const float*)d_in[2];
  const int*   labels  = (const int*)d_in[3];

  char* ws = (char*)d_ws;
  unsigned char* sf8 = (unsigned char*)ws;                  // 2 MiB fp8
  float2* meta = (float2*)(ws + (size_t)NROWS * KDIM);      // 64 KiB
  float* out   = (float*)d_out;

  prep_kernel<<<GRID, 256, 0, stream>>>(samples, labels, sf8, meta, out);
  pair_kernel<<<GRID, 512, 0, stream>>>(sf8, meta, out);
}